// Round 25
// baseline (126.874 us; speedup 1.0000x reference)
//
#include <hip/hip_runtime.h>
#include <cstdint>
#include <cstddef>

#define NHEAD 8
#define HDIM 32
#define DMODEL 256
#define NLEVEL 4
#define NPOINT 4

using short8 = __attribute__((ext_vector_type(8))) short;
using f32x4  = __attribute__((ext_vector_type(4))) float;

// ---- bf16 helpers (RNE) ----------------------------------------------------
__device__ __forceinline__ unsigned short f2bf(float x) {
    unsigned int b = __float_as_uint(x);
    unsigned int r = b + 0x7FFFu + ((b >> 16) & 1u);
    return (unsigned short)(r >> 16);
}
__device__ __forceinline__ float bf2f(unsigned short u) {
    return __uint_as_float(((unsigned int)u) << 16);
}
__device__ __forceinline__ unsigned short lo1(float v) {
    const unsigned short h = f2bf(v);
    return f2bf(v - bf2f(h));
}
__device__ __forceinline__ unsigned int pk2(unsigned short a, unsigned short b) {
    return (unsigned int)a | ((unsigned int)b << 16);
}

// ---------------------------------------------------------------------------
// convall: ONE launch for all conversions.
//   blocks [0, nbAct): value -> Av, query -> Aq  ([hi|lo] per row)
//   blocks [nbAct, nbAct+192): four weight matrices -> Bv, Bo, Blg
// ---------------------------------------------------------------------------
__global__ __launch_bounds__(256) void convall(
    const float* __restrict__ value, const float* __restrict__ query,
    unsigned short* __restrict__ Av, unsigned short* __restrict__ Aq,
    int M2, int Mtot, int nbAct,
    const float* __restrict__ w0, const float* __restrict__ w1,
    const float* __restrict__ w2, const float* __restrict__ w3,
    unsigned short* __restrict__ b0, unsigned short* __restrict__ b1,
    unsigned short* __restrict__ blg)
{
    if ((int)blockIdx.x < nbAct) {
        const int idx = blockIdx.x * 256 + threadIdx.x;
        if (idx >= Mtot * 64) return;
        const int r = idx >> 6, c = (idx & 63) << 2;
        const float* src;
        unsigned short* dst;
        if (r < M2) { src = value + (size_t)r * 256; dst = Av + (size_t)r * 512; }
        else { src = query + (size_t)(r - M2) * 256; dst = Aq + (size_t)(r - M2) * 512; }
        const float4 v = *(const float4*)(src + c);
        ushort4 hi, lo;
        hi.x = f2bf(v.x); lo.x = lo1(v.x);
        hi.y = f2bf(v.y); lo.y = lo1(v.y);
        hi.z = f2bf(v.z); lo.z = lo1(v.z);
        hi.w = f2bf(v.w); lo.w = lo1(v.w);
        *(ushort4*)(dst + c)       = hi;
        *(ushort4*)(dst + 256 + c) = lo;
    } else {
        const int bx = (int)blockIdx.x - nbAct;           // 0..191
        int y, base;
        if (bx < 64)       { y = 0; base = bx; }
        else if (bx < 128) { y = 1; base = bx - 64; }
        else if (bx < 160) { y = 2; base = bx - 128; }
        else               { y = 3; base = bx - 160; }
        const float* src = (y == 0) ? w0 : (y == 1) ? w1 : (y == 2) ? w2 : w3;
        unsigned short* dst = (y == 0) ? b0 : (y == 1) ? b1 : (y == 2) ? blg : (blg + 128 * 512);
        const int rows = (y < 2) ? 256 : 128;
        const int idx = base * 256 + threadIdx.x;
        if (idx >= rows * 64) return;
        const int r = idx >> 6, c = (idx & 63) << 2;
        const float4 v = *(const float4*)(src + (size_t)r * 256 + c);
        ushort4 hi, lo;
        hi.x = f2bf(v.x); lo.x = lo1(v.x);
        hi.y = f2bf(v.y); lo.y = lo1(v.y);
        hi.z = f2bf(v.z); lo.z = lo1(v.z);
        hi.w = f2bf(v.w); lo.w = lo1(v.w);
        *(ushort4*)(dst + (size_t)r * 512 + c)       = hi;
        *(ushort4*)(dst + (size_t)r * 512 + 256 + c) = lo;
    }
}

// ---------------------------------------------------------------------------
// Split-bf16 MFMA GEMM, BM=32 x BN=256, BK=64, 12 K-steps, single-buffered
// (R24-proven, 36KB LDS), now with 2-DEEP register prefetch: loads for step
// st+2 issue at step st (two named reg sets, uniform parity select -- rule
// #20 keeps them in registers). Doubles the latency-hiding window to ~2
// steps (>= ~500cy load latency) at +36 VGPR (~120 total, under the 128 cap).
// K'=768 = 12x64: A segs [hi,hi,lo] x B segs [hi,lo,hi] (C = AhBh+AhBl+AlBh).
// Swizzle phys_row = row^(slot<<1). obf: bf16 C-write for vprj.
// ---------------------------------------------------------------------------
#define AOFF(sn) ((((sn) >> 2) < 2) ? (((sn) & 3) << 6) : 256 + (((sn) & 3) << 6))
#define BOFF(sn) ((((sn) >> 2) == 1) ? 256 + (((sn) & 3) << 6) : (((sn) & 3) << 6))

#define STAGE_LOAD(S, off_a, off_b) { \
    va##S  = *(const uint4*)(pA + (off_a)); \
    vb0##S = *(const uint4*)(pB + (off_b)); \
    vb1##S = *(const uint4*)(pB + (off_b) + (size_t) 32*512); \
    vb2##S = *(const uint4*)(pB + (off_b) + (size_t) 64*512); \
    vb3##S = *(const uint4*)(pB + (off_b) + (size_t) 96*512); \
    vb4##S = *(const uint4*)(pB + (off_b) + (size_t)128*512); \
    vb5##S = *(const uint4*)(pB + (off_b) + (size_t)160*512); \
    vb6##S = *(const uint4*)(pB + (off_b) + (size_t)192*512); \
    vb7##S = *(const uint4*)(pB + (off_b) + (size_t)224*512); }

#define STAGE_STORE(S) { \
    *(uint4*)&As[as * 256 + arx * 8] = va##S; \
    *(uint4*)&Bs[bs * 2048 + (brx      ) * 8] = vb0##S; \
    *(uint4*)&Bs[bs * 2048 + (brx +  32) * 8] = vb1##S; \
    *(uint4*)&Bs[bs * 2048 + (brx +  64) * 8] = vb2##S; \
    *(uint4*)&Bs[bs * 2048 + (brx +  96) * 8] = vb3##S; \
    *(uint4*)&Bs[bs * 2048 + (brx + 128) * 8] = vb4##S; \
    *(uint4*)&Bs[bs * 2048 + (brx + 160) * 8] = vb5##S; \
    *(uint4*)&Bs[bs * 2048 + (brx + 192) * 8] = vb6##S; \
    *(uint4*)&Bs[bs * 2048 + (brx + 224) * 8] = vb7##S; }

template<int ID>
__global__ __launch_bounds__(256, 4) void gemm_mfma(
    const unsigned short* __restrict__ A0, const unsigned short* __restrict__ B0,
    const float* __restrict__ bsA0, const float* __restrict__ bsB0, int bsplit0,
    const unsigned char* __restrict__ mask0, void* __restrict__ C0, int obf0, int M0, int nb0,
    const unsigned short* __restrict__ A1, const unsigned short* __restrict__ B1,
    const float* __restrict__ bsA1, const float* __restrict__ bsB1, int bsplit1,
    const unsigned char* __restrict__ mask1, void* __restrict__ C1, int obf1, int M1)
{
    __shared__ __align__(16) unsigned short As[8 * 32 * 8];    // 4KB  [slot][32][8]
    __shared__ __align__(16) unsigned short Bs[8 * 256 * 8];   // 32KB [slot][256][8]

    const bool second = ((int)blockIdx.x >= nb0);
    const unsigned short* Abf = second ? A1 : A0;
    const unsigned short* Bbf = second ? B1 : B0;
    const float* biasA = second ? bsA1 : bsA0;
    const float* biasB = second ? bsB1 : bsB0;
    const int bsplit   = second ? bsplit1 : bsplit0;
    const unsigned char* maskp = second ? mask1 : mask0;
    void* Cv    = second ? C1 : C0;
    const int obf = second ? obf1 : obf0;
    const int M = second ? M1 : M0;
    const int row0 = (second ? ((int)blockIdx.x - nb0) : (int)blockIdx.x) * 32;

    const int tid  = threadIdx.x;
    const int lane = tid & 63;
    const int wave = tid >> 6;          // 0..3 -> cols wave*64..+64
    const int lr = lane & 15;
    const int kg = lane >> 4;           // 0..3 k-octet group within K=32

    // staging maps (1 A + 8 B loads per thread)
    const int as = tid & 7;             // A slot 0..7
    const int ar = tid >> 3;            // A row 0..31
    const int arx = ar ^ (as << 1);
    const int bs = tid & 7;             // B slot 0..7
    const int br = tid >> 3;            // B row base 0..31 (8 rows stride 32)
    const int brx = br ^ (bs << 1);

    const unsigned short* pA = Abf + (size_t)min(row0 + ar, M - 1) * 512 + as * 8;
    const unsigned short* pB = Bbf + (size_t)br * 512 + bs * 8;

    f32x4 acc[2][4];
#pragma unroll
    for (int m = 0; m < 2; ++m)
#pragma unroll
        for (int n = 0; n < 4; ++n) acc[m][n] = {0.f, 0.f, 0.f, 0.f};

    // two staging register sets: preload steps 0 and 1
    uint4 va0_, vb00_, vb10_, vb20_, vb30_, vb40_, vb50_, vb60_, vb70_;
    uint4 va1_, vb01_, vb11_, vb21_, vb31_, vb41_, vb51_, vb61_, vb71_;
    #define va0  va0_
    #define vb00 vb00_
    // (macro token-paste uses suffix S: declare aliases matching STAGE_* names)
    #undef va0
    #undef vb00

    // rename for macro use: set 0 -> suffix A_, set 1 -> suffix B_
    uint4 vaA_, vb0A_, vb1A_, vb2A_, vb3A_, vb4A_, vb5A_, vb6A_, vb7A_;
    uint4 vaB_, vb0B_, vb1B_, vb2B_, vb3B_, vb4B_, vb5B_, vb6B_, vb7B_;
    (void)va0_; (void)vb00_; (void)vb10_; (void)vb20_; (void)vb30_;
    (void)vb40_; (void)vb50_; (void)vb60_; (void)vb70_;
    (void)va1_; (void)vb01_; (void)vb11_; (void)vb21_; (void)vb31_;
    (void)vb41_; (void)vb51_; (void)vb61_; (void)vb71_;

    STAGE_LOAD(A_, AOFF(0), BOFF(0));
    STAGE_LOAD(B_, AOFF(1), BOFF(1));

    for (int st = 0; st < 12; ++st) {
        if (st & 1) { STAGE_STORE(B_); } else { STAGE_STORE(A_); }
        __syncthreads();   // writes visible before reads

        if (st < 10) {     // issue step st+2's loads: ~2 steps of latency cover
            const int sn = st + 2;
            const int aoff = AOFF(sn);
            const int boff = BOFF(sn);
            if (st & 1) { STAGE_LOAD(B_, aoff, boff); }
            else        { STAGE_LOAD(A_, aoff, boff); }
        }

#pragma unroll
        for (int ks = 0; ks < 2; ++ks) {
            const int sA = ks * 4 + kg;               // octet slot 0..7
            const int rx = lr ^ (sA << 1);
            const short8 a0 = *(const short8*)&As[sA * 256 + (rx     ) * 8];
            const short8 a1 = *(const short8*)&As[sA * 256 + (rx + 16) * 8];
#pragma unroll
            for (int n = 0; n < 4; ++n) {
                const short8 bb = *(const short8*)&Bs[sA * 2048 + (wave * 64 + n * 16 + rx) * 8];
                acc[0][n] = __builtin_amdgcn_mfma_f32_16x16x32_bf16(a0, bb, acc[0][n], 0, 0, 0);
                acc[1][n] = __builtin_amdgcn_mfma_f32_16x16x32_bf16(a1, bb, acc[1][n], 0, 0, 0);
            }
        }
        __syncthreads();   // reads done before next step's writes
    }

    // epilogue: C/D layout col=lane&15, row=(lane>>4)*4+j  [m89-verified]
#pragma unroll
    for (int m = 0; m < 2; ++m) {
#pragma unroll
        for (int n = 0; n < 4; ++n) {
            const int colg = wave * 64 + n * 16 + lr;
            const float bias = (colg < bsplit) ? biasA[colg] : biasB[colg - bsplit];
#pragma unroll
            for (int j = 0; j < 4; ++j) {
                const int rowg = row0 + m * 16 + kg * 4 + j;
                if (rowg < M) {
                    float o = acc[m][n][j] + bias;
                    if (maskp && maskp[rowg]) o = 0.f;
                    if (obf) ((unsigned short*)Cv)[(size_t)rowg * 256 + colg] = f2bf(o);
                    else     ((float*)Cv)[(size_t)rowg * 256 + colg] = o;
                }
            }
        }
    }
}

// ---------------------------------------------------------------------------
// Box-attention sampling (R21-proven: ~37us). bf16-v + point-split + TLP
// (__launch_bounds__(256,5), unroll 4). Output: split-bf16 [hi|lo].
// ---------------------------------------------------------------------------
#define ROWS 4
#define PP 17

__global__ __launch_bounds__(256, 5) void box_sample(
    const unsigned short* __restrict__ v, // (B*L2, 256) bf16 projected value
    const float* __restrict__ alogp,  // attn logits base (stride 256)
    const float* __restrict__ blgp,   // box logits base (stride 256)
    const float* __restrict__ rwin,
    const float* __restrict__ vratio,
    unsigned short* __restrict__ outs, // (B*L1, 512) split-bf16 out
    int M1, int L1, int L2)
{
    __shared__ int   s_idx[ROWS][NHEAD][PP][4];
    __shared__ float s_w  [ROWS][NHEAD][PP][4];
    __shared__ float s_red[ROWS][NHEAD][4][8];   // point-half reduction (4KB)

    const int row0 = blockIdx.x * ROWS;
    const int tid  = threadIdx.x;

    // ================= phase 1 (first 128 threads) =================
    if (tid < 128) {
        const int l  = tid & 3;
        const int hh = (tid >> 2) & 7;
        const int r  = tid >> 5;
        const int rowq = row0 + r;
        if (rowq < M1) {
            const int b = (rowq >= L1) ? 1 : 0;
            float la[16];
            const float* al = alogp + (size_t)rowq * 256 + hh * 16;
            {
                const float4 q0 = *(const float4*)(al + 0);
                const float4 q1 = *(const float4*)(al + 4);
                const float4 q2 = *(const float4*)(al + 8);
                const float4 q3 = *(const float4*)(al + 12);
                la[0]=q0.x; la[1]=q0.y; la[2]=q0.z; la[3]=q0.w;
                la[4]=q1.x; la[5]=q1.y; la[6]=q1.z; la[7]=q1.w;
                la[8]=q2.x; la[9]=q2.y; la[10]=q2.z; la[11]=q2.w;
                la[12]=q3.x; la[13]=q3.y; la[14]=q3.z; la[15]=q3.w;
            }
            float m = la[0];
#pragma unroll
            for (int i = 1; i < 16; i++) m = fmaxf(m, la[i]);
            float s = 0.f;
#pragma unroll
            for (int i = 0; i < 16; i++) { la[i] = __expf(la[i] - m); s += la[i]; }
            const float inv = 1.f / s;

            const int H  = (l == 0) ? 76 : (l == 1) ? 38 : (l == 2) ? 19 : 10;
            const int W  = H;
            const int s0 = (l == 0) ? 0  : (l == 1) ? 5776 : (l == 2) ? 7220 : 7581;

            const float4 ob = *(const float4*)(blgp + (size_t)rowq * 256 + hh * 16 + l * 4);
            const float4 rw = *(const float4*)(rwin + (size_t)rowq * 4);
            const float vrx = vratio[(b * NLEVEL + l) * 2 + 0];
            const float vry = vratio[(b * NLEVEL + l) * 2 + 1];

            const float cx = rw.x + ob.x * 0.125f * rw.z;
            const float cy = rw.y + ob.y * 0.125f * rw.w;
            const float sw = fmaxf(rw.z + ob.z * 0.125f * rw.z, 0.f);
            const float sh = fmaxf(rw.w + ob.w * 0.125f * rw.w, 0.f);

            const int vbase = (b * L2 + s0) * DMODEL + hh * HDIM;  // ushort units

#pragma unroll
            for (int p = 0; p < 4; ++p) {
                const float kx = (p & 1)  ? 0.25f : -0.25f;
                const float ky = (p >> 1) ? 0.25f : -0.25f;
                const float gx = (cx + kx * sw) * vrx;
                const float gy = (cy + ky * sh) * vry;
                const float x = gx * (float)W - 0.5f;
                const float y = gy * (float)H - 0.5f;
                const float x0f = floorf(x);
                const float y0f = floorf(y);
                const float lx = x - x0f, ly = y - y0f;
                const int x0 = (int)x0f, y0 = (int)y0f;
                const float aw = la[l * 4 + p] * inv;
                const float wb[4] = { (1.f - ly) * (1.f - lx) * aw,
                                      (1.f - ly) * lx * aw,
                                      ly * (1.f - lx) * aw,
                                      ly * lx * aw };
                const int lp = l * 4 + p;
#pragma unroll
                for (int j = 0; j < 4; ++j) {
                    const int yy = y0 + (j >> 1);
                    const int xx = x0 + (j & 1);
                    const bool ok = (yy >= 0) & (yy < H) & (xx >= 0) & (xx < W);
                    const int yc = min(max(yy, 0), H - 1);
                    const int xc = min(max(xx, 0), W - 1);
                    s_idx[r][hh][lp][j] = vbase + (yc * W + xc) * DMODEL;
                    s_w  [r][hh][lp][j] = ok ? wb[j] : 0.f;
                }
            }
        }
    }
    __syncthreads();

    // ================= phase 2: point-split ushort8 gathers =================
    {
        const int oct = tid & 3;            // channel octet 0..3
        const int hh  = (tid >> 2) & 7;     // head
        const int ph  = (tid >> 5) & 1;     // point half
        const int r   = tid >> 6;           // row 0..3
        const int rowq = row0 + r;
        const int c8 = oct << 3;
        float acc[8];
#pragma unroll
        for (int k = 0; k < 8; ++k) acc[k] = 0.f;

        if (rowq < M1) {
            const int p0 = ph << 3;
#pragma unroll 4
            for (int pi = 0; pi < 8; ++pi) {
                const int p = p0 + pi;
                const int4   iv = *(const int4  *)&s_idx[r][hh][p][0];
                const float4 wv = *(const float4*)&s_w  [r][hh][p][0];
                const uint4 g0 = *(const uint4*)(v + iv.x + c8);
                const uint4 g1 = *(const uint4*)(v + iv.y + c8);
                const uint4 g2 = *(const uint4*)(v + iv.z + c8);
                const uint4 g3 = *(const uint4*)(v + iv.w + c8);
                const unsigned int u0[4] = {g0.x, g0.y, g0.z, g0.w};
                const unsigned int u1[4] = {g1.x, g1.y, g1.z, g1.w};
                const unsigned int u2[4] = {g2.x, g2.y, g2.z, g2.w};
                const unsigned int u3[4] = {g3.x, g3.y, g3.z, g3.w};
#pragma unroll
                for (int j = 0; j < 4; ++j) {
                    const float a0 = __uint_as_float(u0[j] << 16);
                    const float b0 = __uint_as_float(u0[j] & 0xffff0000u);
                    const float a1 = __uint_as_float(u1[j] << 16);
                    const float b1 = __uint_as_float(u1[j] & 0xffff0000u);
                    const float a2 = __uint_as_float(u2[j] << 16);
                    const float b2 = __uint_as_float(u2[j] & 0xffff0000u);
                    const float a3 = __uint_as_float(u3[j] << 16);
                    const float b3 = __uint_as_float(u3[j] & 0xffff0000u);
                    acc[j * 2]     += wv.x * a0 + wv.y * a1 + wv.z * a2 + wv.w * a3;
                    acc[j * 2 + 1] += wv.x * b0 + wv.y * b1 + wv.z * b2 + wv.w * b3;
                }
            }
        }

        // reduce the two point-halves via LDS
        if (ph == 1) {
#pragma unroll
            for (int k = 0; k < 8; ++k) s_red[r][hh][oct][k] = acc[k];
        }
        __syncthreads();
        if (ph == 0 && rowq < M1) {
#pragma unroll
            for (int k = 0; k < 8; ++k) acc[k] += s_red[r][hh][oct][k];
            uint4 hi, lo;
            hi.x = pk2(f2bf(acc[0]), f2bf(acc[1]));
            hi.y = pk2(f2bf(acc[2]), f2bf(acc[3]));
            hi.z = pk2(f2bf(acc[4]), f2bf(acc[5]));
            hi.w = pk2(f2bf(acc[6]), f2bf(acc[7]));
            lo.x = pk2(lo1(acc[0]), lo1(acc[1]));
            lo.y = pk2(lo1(acc[2]), lo1(acc[3]));
            lo.z = pk2(lo1(acc[4]), lo1(acc[5]));
            lo.w = pk2(lo1(acc[6]), lo1(acc[7]));
            *(uint4*)(outs + (size_t)rowq * 512 + hh * HDIM + c8)       = hi;
            *(uint4*)(outs + (size_t)rowq * 512 + 256 + hh * HDIM + c8) = lo;
        }
    }
}

// ---------------------------------------------------------------------------
extern "C" void kernel_launch(void* const* d_in, const int* in_sizes, int n_in,
                              void* d_out, int out_size, void* d_ws, size_t ws_size,
                              hipStream_t stream) {
    const float* query   = (const float*)d_in[0];
    const float* value   = (const float*)d_in[1];
    const unsigned char* v_mask = (const unsigned char*)d_in[3];
    const float* v_valid = (const float*)d_in[5];
    const float* ref_win = (const float*)d_in[6];
    const float* vproj_w = (const float*)d_in[7];
    const float* vproj_b = (const float*)d_in[8];
    const float* oproj_w = (const float*)d_in[9];
    const float* oproj_b = (const float*)d_in[10];
    const float* box_w   = (const float*)d_in[11];
    const float* box_b   = (const float*)d_in[12];
    const float* attn_w  = (const float*)d_in[13];
    const float* attn_b  = (const float*)d_in[14];

    const int B  = 2;
    const int M1 = in_sizes[0] / DMODEL;   // B*L1
    const int M2 = in_sizes[1] / DMODEL;   // B*L2
    const int L1 = M1 / B;
    const int L2 = M2 / B;
    const dim3 blk(256);

    // ---- workspace plan: Av | Aq(->OutS) | vprj(bf16) | weights; lgt in d_out
    const size_t szAv = (size_t)M2 * 512 * 2;
    const size_t szAq = (size_t)M1 * 512 * 2;
    char* wsb = (char*)d_ws;
    unsigned short* Av   = (unsigned short*)(wsb);
    unsigned short* Aq   = (unsigned short*)(wsb + szAv);
    unsigned short* OutS = Aq;                       // alias: Aq dead after GEMM
    unsigned short* vprj = (unsigned short*)(wsb + szAv + szAq);   // bf16 M2*256
    unsigned short* Bv   = (unsigned short*)(wsb + szAv + szAq + (size_t)M2 * 256 * 2);
    unsigned short* Bo   = Bv + 256 * 512;
    unsigned short* Blg  = Bo + 256 * 512;
    float*          lgt  = (float*)d_out;            // scratch until final GEMM

    const int mb1 = (M1 + 31) / 32;
    const int mb2 = (M2 + 31) / 32;
    const int nbAct = ((M2 + M1) * 64 + 255) / 256;

    // 1) ALL conversions in one launch (activations + 4 weight matrices)
    convall<<<dim3(nbAct + 192), blk, 0, stream>>>(
        value, query, Av, Aq, M2, M2 + M1, nbAct,
        vproj_w, oproj_w, attn_w, box_w, Bv, Bo, Blg);

    // 2) MERGED: value projection (+mask, bf16 out) AND combined logits (f32)
    gemm_mfma<0><<<dim3(mb2 + mb1), blk, 0, stream>>>(
        Av, Bv, vproj_b, vproj_b, 256, v_mask, (void*)vprj, 1, M2, mb2,
        Aq, Blg, attn_b, box_b, 128, nullptr, (void*)lgt, 0, M1);

    // 3) sampling (bf16 v gathers, point-split, TLP) -> split-bf16
    box_sample<<<dim3((M1 + ROWS - 1) / ROWS), blk, 0, stream>>>(
        vprj, lgt, lgt + 128, ref_win, v_valid, OutS, M1, L1, L2);

    // 4) output projection (reads OutS, overwrites d_out)
    gemm_mfma<1><<<dim3(mb1), blk, 0, stream>>>(
        OutS, Bo, oproj_b, oproj_b, 256, nullptr, d_out, 0, M1, mb1,
        OutS, Bo, oproj_b, oproj_b, 256, nullptr, d_out, 0, M1);
}

// Round 26
// 97.415 us; speedup vs baseline: 1.3024x; 1.3024x over previous
//
#include <hip/hip_runtime.h>
#include <cstdint>
#include <cstddef>

#define NHEAD 8
#define HDIM 32
#define DMODEL 256
#define NLEVEL 4
#define NPOINT 4

using short8 = __attribute__((ext_vector_type(8))) short;
using f32x4  = __attribute__((ext_vector_type(4))) float;

// ---- bf16 helpers (RNE) ----------------------------------------------------
__device__ __forceinline__ unsigned short f2bf(float x) {
    unsigned int b = __float_as_uint(x);
    unsigned int r = b + 0x7FFFu + ((b >> 16) & 1u);
    return (unsigned short)(r >> 16);
}
__device__ __forceinline__ float bf2f(unsigned short u) {
    return __uint_as_float(((unsigned int)u) << 16);
}
__device__ __forceinline__ unsigned short lo1(float v) {
    const unsigned short h = f2bf(v);
    return f2bf(v - bf2f(h));
}
__device__ __forceinline__ unsigned int pk2(unsigned short a, unsigned short b) {
    return (unsigned int)a | ((unsigned int)b << 16);
}

// ---------------------------------------------------------------------------
// convall: ONE launch for all conversions.
//   blocks [0, nbAct): value -> Av, query -> Aq  ([hi|lo] per row)
//   blocks [nbAct, nbAct+192): four weight matrices -> Bv, Bo, Blg
// ---------------------------------------------------------------------------
__global__ __launch_bounds__(256) void convall(
    const float* __restrict__ value, const float* __restrict__ query,
    unsigned short* __restrict__ Av, unsigned short* __restrict__ Aq,
    int M2, int Mtot, int nbAct,
    const float* __restrict__ w0, const float* __restrict__ w1,
    const float* __restrict__ w2, const float* __restrict__ w3,
    unsigned short* __restrict__ b0, unsigned short* __restrict__ b1,
    unsigned short* __restrict__ blg)
{
    if ((int)blockIdx.x < nbAct) {
        const int idx = blockIdx.x * 256 + threadIdx.x;
        if (idx >= Mtot * 64) return;
        const int r = idx >> 6, c = (idx & 63) << 2;
        const float* src;
        unsigned short* dst;
        if (r < M2) { src = value + (size_t)r * 256; dst = Av + (size_t)r * 512; }
        else { src = query + (size_t)(r - M2) * 256; dst = Aq + (size_t)(r - M2) * 512; }
        const float4 v = *(const float4*)(src + c);
        ushort4 hi, lo;
        hi.x = f2bf(v.x); lo.x = lo1(v.x);
        hi.y = f2bf(v.y); lo.y = lo1(v.y);
        hi.z = f2bf(v.z); lo.z = lo1(v.z);
        hi.w = f2bf(v.w); lo.w = lo1(v.w);
        *(ushort4*)(dst + c)       = hi;
        *(ushort4*)(dst + 256 + c) = lo;
    } else {
        const int bx = (int)blockIdx.x - nbAct;           // 0..191
        int y, base;
        if (bx < 64)       { y = 0; base = bx; }
        else if (bx < 128) { y = 1; base = bx - 64; }
        else if (bx < 160) { y = 2; base = bx - 128; }
        else               { y = 3; base = bx - 160; }
        const float* src = (y == 0) ? w0 : (y == 1) ? w1 : (y == 2) ? w2 : w3;
        unsigned short* dst = (y == 0) ? b0 : (y == 1) ? b1 : (y == 2) ? blg : (blg + 128 * 512);
        const int rows = (y < 2) ? 256 : 128;
        const int idx = base * 256 + threadIdx.x;
        if (idx >= rows * 64) return;
        const int r = idx >> 6, c = (idx & 63) << 2;
        const float4 v = *(const float4*)(src + (size_t)r * 256 + c);
        ushort4 hi, lo;
        hi.x = f2bf(v.x); lo.x = lo1(v.x);
        hi.y = f2bf(v.y); lo.y = lo1(v.y);
        hi.z = f2bf(v.z); lo.z = lo1(v.z);
        hi.w = f2bf(v.w); lo.w = lo1(v.w);
        *(ushort4*)(dst + (size_t)r * 512 + c)       = hi;
        *(ushort4*)(dst + (size_t)r * 512 + 256 + c) = lo;
    }
}

// ---------------------------------------------------------------------------
// Split-bf16 MFMA GEMM, BM=32 x BN=256, BK=64, 12 K-steps, single-buffered,
// 1-DEEP register prefetch (R24-proven; R25's 2-deep spilled 72 staging
// VGPRs to scratch -- WRITE_SIZE 23->104MB -- and regressed 30us).
// LDS 36KB: [slot 0..7][rows][8] per operand; swizzle phys_row = row^(slot<<1).
// K'=768 = 12x64: A segs [hi,hi,lo] x B segs [hi,lo,hi] (C = AhBh+AhBl+AlBh).
// Two sub-GEMMs merged per launch. obf: bf16 C-write for vprj.
// ---------------------------------------------------------------------------
template<int ID>
__global__ __launch_bounds__(256, 4) void gemm_mfma(
    const unsigned short* __restrict__ A0, const unsigned short* __restrict__ B0,
    const float* __restrict__ bsA0, const float* __restrict__ bsB0, int bsplit0,
    const unsigned char* __restrict__ mask0, void* __restrict__ C0, int obf0, int M0, int nb0,
    const unsigned short* __restrict__ A1, const unsigned short* __restrict__ B1,
    const float* __restrict__ bsA1, const float* __restrict__ bsB1, int bsplit1,
    const unsigned char* __restrict__ mask1, void* __restrict__ C1, int obf1, int M1)
{
    __shared__ __align__(16) unsigned short As[8 * 32 * 8];    // 4KB  [slot][32][8]
    __shared__ __align__(16) unsigned short Bs[8 * 256 * 8];   // 32KB [slot][256][8]

    const bool second = ((int)blockIdx.x >= nb0);
    const unsigned short* Abf = second ? A1 : A0;
    const unsigned short* Bbf = second ? B1 : B0;
    const float* biasA = second ? bsA1 : bsA0;
    const float* biasB = second ? bsB1 : bsB0;
    const int bsplit   = second ? bsplit1 : bsplit0;
    const unsigned char* maskp = second ? mask1 : mask0;
    void* Cv    = second ? C1 : C0;
    const int obf = second ? obf1 : obf0;
    const int M = second ? M1 : M0;
    const int row0 = (second ? ((int)blockIdx.x - nb0) : (int)blockIdx.x) * 32;

    const int tid  = threadIdx.x;
    const int lane = tid & 63;
    const int wave = tid >> 6;          // 0..3 -> cols wave*64..+64
    const int lr = lane & 15;
    const int kg = lane >> 4;           // 0..3 k-octet group within K=32

    // staging maps (1 A + 8 B loads per thread)
    const int as = tid & 7;             // A slot 0..7
    const int ar = tid >> 3;            // A row 0..31
    const int arx = ar ^ (as << 1);
    const int bs = tid & 7;             // B slot 0..7
    const int br = tid >> 3;            // B row base 0..31 (8 rows stride 32)

    const unsigned short* pA = Abf + (size_t)min(row0 + ar, M - 1) * 512 + as * 8;
    const unsigned short* pB = Bbf + (size_t)br * 512 + bs * 8;

    f32x4 acc[2][4];
#pragma unroll
    for (int m = 0; m < 2; ++m)
#pragma unroll
        for (int n = 0; n < 4; ++n) acc[m][n] = {0.f, 0.f, 0.f, 0.f};

    // prefetch step 0 (seg0: aoff=boff=0)
    uint4 va, vb0, vb1, vb2, vb3, vb4, vb5, vb6, vb7;
    va  = *(const uint4*)pA;
    vb0 = *(const uint4*)(pB                   );
    vb1 = *(const uint4*)(pB + (size_t) 32*512);
    vb2 = *(const uint4*)(pB + (size_t) 64*512);
    vb3 = *(const uint4*)(pB + (size_t) 96*512);
    vb4 = *(const uint4*)(pB + (size_t)128*512);
    vb5 = *(const uint4*)(pB + (size_t)160*512);
    vb6 = *(const uint4*)(pB + (size_t)192*512);
    vb7 = *(const uint4*)(pB + (size_t)224*512);

    for (int st = 0; st < 12; ++st) {
        *(uint4*)&As[as * 256 + arx * 8] = va;
        *(uint4*)&Bs[bs * 2048 + (((br      ) ^ (bs << 1))      ) * 8] = vb0;
        *(uint4*)&Bs[bs * 2048 + (((br      ) ^ (bs << 1)) +  32) * 8] = vb1;
        *(uint4*)&Bs[bs * 2048 + (((br      ) ^ (bs << 1)) +  64) * 8] = vb2;
        *(uint4*)&Bs[bs * 2048 + (((br      ) ^ (bs << 1)) +  96) * 8] = vb3;
        *(uint4*)&Bs[bs * 2048 + (((br      ) ^ (bs << 1)) + 128) * 8] = vb4;
        *(uint4*)&Bs[bs * 2048 + (((br      ) ^ (bs << 1)) + 160) * 8] = vb5;
        *(uint4*)&Bs[bs * 2048 + (((br      ) ^ (bs << 1)) + 192) * 8] = vb6;
        *(uint4*)&Bs[bs * 2048 + (((br      ) ^ (bs << 1)) + 224) * 8] = vb7;
        __syncthreads();   // writes visible before reads

        if (st < 11) {     // issue next step's loads; hide under 16 MFMAs
            const int sn   = st + 1;
            const int seg  = sn >> 2;                 // 0..2
            const int kl   = (sn & 3) << 6;           // 0,64,128,192 (ushort)
            const int aoff = (seg < 2)  ? kl : 256 + kl;   // A: [hi,hi,lo]
            const int boff = (seg == 1) ? 256 + kl : kl;   // B: [hi,lo,hi]
            va  = *(const uint4*)(pA + aoff);
            vb0 = *(const uint4*)(pB + boff                   );
            vb1 = *(const uint4*)(pB + boff + (size_t) 32*512);
            vb2 = *(const uint4*)(pB + boff + (size_t) 64*512);
            vb3 = *(const uint4*)(pB + boff + (size_t) 96*512);
            vb4 = *(const uint4*)(pB + boff + (size_t)128*512);
            vb5 = *(const uint4*)(pB + boff + (size_t)160*512);
            vb6 = *(const uint4*)(pB + boff + (size_t)192*512);
            vb7 = *(const uint4*)(pB + boff + (size_t)224*512);
        }

#pragma unroll
        for (int ks = 0; ks < 2; ++ks) {
            const int sA = ks * 4 + kg;               // octet slot 0..7
            const int rx = lr ^ (sA << 1);
            const short8 a0 = *(const short8*)&As[sA * 256 + (rx     ) * 8];
            const short8 a1 = *(const short8*)&As[sA * 256 + (rx + 16) * 8];
#pragma unroll
            for (int n = 0; n < 4; ++n) {
                const short8 bb = *(const short8*)&Bs[sA * 2048 + (wave * 64 + n * 16 + rx) * 8];
                acc[0][n] = __builtin_amdgcn_mfma_f32_16x16x32_bf16(a0, bb, acc[0][n], 0, 0, 0);
                acc[1][n] = __builtin_amdgcn_mfma_f32_16x16x32_bf16(a1, bb, acc[1][n], 0, 0, 0);
            }
        }
        __syncthreads();   // reads done before next step's writes
    }

    // epilogue: C/D layout col=lane&15, row=(lane>>4)*4+j  [m89-verified]
#pragma unroll
    for (int m = 0; m < 2; ++m) {
#pragma unroll
        for (int n = 0; n < 4; ++n) {
            const int colg = wave * 64 + n * 16 + lr;
            const float bias = (colg < bsplit) ? biasA[colg] : biasB[colg - bsplit];
#pragma unroll
            for (int j = 0; j < 4; ++j) {
                const int rowg = row0 + m * 16 + kg * 4 + j;
                if (rowg < M) {
                    float o = acc[m][n][j] + bias;
                    if (maskp && maskp[rowg]) o = 0.f;
                    if (obf) ((unsigned short*)Cv)[(size_t)rowg * 256 + colg] = f2bf(o);
                    else     ((float*)Cv)[(size_t)rowg * 256 + colg] = o;
                }
            }
        }
    }
}

// ---------------------------------------------------------------------------
// Box-attention sampling (R21-proven: ~37us). bf16-v + point-split + TLP
// (__launch_bounds__(256,5), unroll 4). Output: split-bf16 [hi|lo].
// ---------------------------------------------------------------------------
#define ROWS 4
#define PP 17

__global__ __launch_bounds__(256, 5) void box_sample(
    const unsigned short* __restrict__ v, // (B*L2, 256) bf16 projected value
    const float* __restrict__ alogp,  // attn logits base (stride 256)
    const float* __restrict__ blgp,   // box logits base (stride 256)
    const float* __restrict__ rwin,
    const float* __restrict__ vratio,
    unsigned short* __restrict__ outs, // (B*L1, 512) split-bf16 out
    int M1, int L1, int L2)
{
    __shared__ int   s_idx[ROWS][NHEAD][PP][4];
    __shared__ float s_w  [ROWS][NHEAD][PP][4];
    __shared__ float s_red[ROWS][NHEAD][4][8];   // point-half reduction (4KB)

    const int row0 = blockIdx.x * ROWS;
    const int tid  = threadIdx.x;

    // ================= phase 1 (first 128 threads) =================
    if (tid < 128) {
        const int l  = tid & 3;
        const int hh = (tid >> 2) & 7;
        const int r  = tid >> 5;
        const int rowq = row0 + r;
        if (rowq < M1) {
            const int b = (rowq >= L1) ? 1 : 0;
            float la[16];
            const float* al = alogp + (size_t)rowq * 256 + hh * 16;
            {
                const float4 q0 = *(const float4*)(al + 0);
                const float4 q1 = *(const float4*)(al + 4);
                const float4 q2 = *(const float4*)(al + 8);
                const float4 q3 = *(const float4*)(al + 12);
                la[0]=q0.x; la[1]=q0.y; la[2]=q0.z; la[3]=q0.w;
                la[4]=q1.x; la[5]=q1.y; la[6]=q1.z; la[7]=q1.w;
                la[8]=q2.x; la[9]=q2.y; la[10]=q2.z; la[11]=q2.w;
                la[12]=q3.x; la[13]=q3.y; la[14]=q3.z; la[15]=q3.w;
            }
            float m = la[0];
#pragma unroll
            for (int i = 1; i < 16; i++) m = fmaxf(m, la[i]);
            float s = 0.f;
#pragma unroll
            for (int i = 0; i < 16; i++) { la[i] = __expf(la[i] - m); s += la[i]; }
            const float inv = 1.f / s;

            const int H  = (l == 0) ? 76 : (l == 1) ? 38 : (l == 2) ? 19 : 10;
            const int W  = H;
            const int s0 = (l == 0) ? 0  : (l == 1) ? 5776 : (l == 2) ? 7220 : 7581;

            const float4 ob = *(const float4*)(blgp + (size_t)rowq * 256 + hh * 16 + l * 4);
            const float4 rw = *(const float4*)(rwin + (size_t)rowq * 4);
            const float vrx = vratio[(b * NLEVEL + l) * 2 + 0];
            const float vry = vratio[(b * NLEVEL + l) * 2 + 1];

            const float cx = rw.x + ob.x * 0.125f * rw.z;
            const float cy = rw.y + ob.y * 0.125f * rw.w;
            const float sw = fmaxf(rw.z + ob.z * 0.125f * rw.z, 0.f);
            const float sh = fmaxf(rw.w + ob.w * 0.125f * rw.w, 0.f);

            const int vbase = (b * L2 + s0) * DMODEL + hh * HDIM;  // ushort units

#pragma unroll
            for (int p = 0; p < 4; ++p) {
                const float kx = (p & 1)  ? 0.25f : -0.25f;
                const float ky = (p >> 1) ? 0.25f : -0.25f;
                const float gx = (cx + kx * sw) * vrx;
                const float gy = (cy + ky * sh) * vry;
                const float x = gx * (float)W - 0.5f;
                const float y = gy * (float)H - 0.5f;
                const float x0f = floorf(x);
                const float y0f = floorf(y);
                const float lx = x - x0f, ly = y - y0f;
                const int x0 = (int)x0f, y0 = (int)y0f;
                const float aw = la[l * 4 + p] * inv;
                const float wb[4] = { (1.f - ly) * (1.f - lx) * aw,
                                      (1.f - ly) * lx * aw,
                                      ly * (1.f - lx) * aw,
                                      ly * lx * aw };
                const int lp = l * 4 + p;
#pragma unroll
                for (int j = 0; j < 4; ++j) {
                    const int yy = y0 + (j >> 1);
                    const int xx = x0 + (j & 1);
                    const bool ok = (yy >= 0) & (yy < H) & (xx >= 0) & (xx < W);
                    const int yc = min(max(yy, 0), H - 1);
                    const int xc = min(max(xx, 0), W - 1);
                    s_idx[r][hh][lp][j] = vbase + (yc * W + xc) * DMODEL;
                    s_w  [r][hh][lp][j] = ok ? wb[j] : 0.f;
                }
            }
        }
    }
    __syncthreads();

    // ================= phase 2: point-split ushort8 gathers =================
    {
        const int oct = tid & 3;            // channel octet 0..3
        const int hh  = (tid >> 2) & 7;     // head
        const int ph  = (tid >> 5) & 1;     // point half
        const int r   = tid >> 6;           // row 0..3
        const int rowq = row0 + r;
        const int c8 = oct << 3;
        float acc[8];
#pragma unroll
        for (int k = 0; k < 8; ++k) acc[k] = 0.f;

        if (rowq < M1) {
            const int p0 = ph << 3;
#pragma unroll 4
            for (int pi = 0; pi < 8; ++pi) {
                const int p = p0 + pi;
                const int4   iv = *(const int4  *)&s_idx[r][hh][p][0];
                const float4 wv = *(const float4*)&s_w  [r][hh][p][0];
                const uint4 g0 = *(const uint4*)(v + iv.x + c8);
                const uint4 g1 = *(const uint4*)(v + iv.y + c8);
                const uint4 g2 = *(const uint4*)(v + iv.z + c8);
                const uint4 g3 = *(const uint4*)(v + iv.w + c8);
                const unsigned int u0[4] = {g0.x, g0.y, g0.z, g0.w};
                const unsigned int u1[4] = {g1.x, g1.y, g1.z, g1.w};
                const unsigned int u2[4] = {g2.x, g2.y, g2.z, g2.w};
                const unsigned int u3[4] = {g3.x, g3.y, g3.z, g3.w};
#pragma unroll
                for (int j = 0; j < 4; ++j) {
                    const float a0 = __uint_as_float(u0[j] << 16);
                    const float b0 = __uint_as_float(u0[j] & 0xffff0000u);
                    const float a1 = __uint_as_float(u1[j] << 16);
                    const float b1 = __uint_as_float(u1[j] & 0xffff0000u);
                    const float a2 = __uint_as_float(u2[j] << 16);
                    const float b2 = __uint_as_float(u2[j] & 0xffff0000u);
                    const float a3 = __uint_as_float(u3[j] << 16);
                    const float b3 = __uint_as_float(u3[j] & 0xffff0000u);
                    acc[j * 2]     += wv.x * a0 + wv.y * a1 + wv.z * a2 + wv.w * a3;
                    acc[j * 2 + 1] += wv.x * b0 + wv.y * b1 + wv.z * b2 + wv.w * b3;
                }
            }
        }

        // reduce the two point-halves via LDS
        if (ph == 1) {
#pragma unroll
            for (int k = 0; k < 8; ++k) s_red[r][hh][oct][k] = acc[k];
        }
        __syncthreads();
        if (ph == 0 && rowq < M1) {
#pragma unroll
            for (int k = 0; k < 8; ++k) acc[k] += s_red[r][hh][oct][k];
            uint4 hi, lo;
            hi.x = pk2(f2bf(acc[0]), f2bf(acc[1]));
            hi.y = pk2(f2bf(acc[2]), f2bf(acc[3]));
            hi.z = pk2(f2bf(acc[4]), f2bf(acc[5]));
            hi.w = pk2(f2bf(acc[6]), f2bf(acc[7]));
            lo.x = pk2(lo1(acc[0]), lo1(acc[1]));
            lo.y = pk2(lo1(acc[2]), lo1(acc[3]));
            lo.z = pk2(lo1(acc[4]), lo1(acc[5]));
            lo.w = pk2(lo1(acc[6]), lo1(acc[7]));
            *(uint4*)(outs + (size_t)rowq * 512 + hh * HDIM + c8)       = hi;
            *(uint4*)(outs + (size_t)rowq * 512 + 256 + hh * HDIM + c8) = lo;
        }
    }
}

// ---------------------------------------------------------------------------
extern "C" void kernel_launch(void* const* d_in, const int* in_sizes, int n_in,
                              void* d_out, int out_size, void* d_ws, size_t ws_size,
                              hipStream_t stream) {
    const float* query   = (const float*)d_in[0];
    const float* value   = (const float*)d_in[1];
    const unsigned char* v_mask = (const unsigned char*)d_in[3];
    const float* v_valid = (const float*)d_in[5];
    const float* ref_win = (const float*)d_in[6];
    const float* vproj_w = (const float*)d_in[7];
    const float* vproj_b = (const float*)d_in[8];
    const float* oproj_w = (const float*)d_in[9];
    const float* oproj_b = (const float*)d_in[10];
    const float* box_w   = (const float*)d_in[11];
    const float* box_b   = (const float*)d_in[12];
    const float* attn_w  = (const float*)d_in[13];
    const float* attn_b  = (const float*)d_in[14];

    const int B  = 2;
    const int M1 = in_sizes[0] / DMODEL;   // B*L1
    const int M2 = in_sizes[1] / DMODEL;   // B*L2
    const int L1 = M1 / B;
    const int L2 = M2 / B;
    const dim3 blk(256);

    // ---- workspace plan: Av | Aq(->OutS) | vprj(bf16) | weights; lgt in d_out
    const size_t szAv = (size_t)M2 * 512 * 2;
    const size_t szAq = (size_t)M1 * 512 * 2;
    char* wsb = (char*)d_ws;
    unsigned short* Av   = (unsigned short*)(wsb);
    unsigned short* Aq   = (unsigned short*)(wsb + szAv);
    unsigned short* OutS = Aq;                       // alias: Aq dead after GEMM
    unsigned short* vprj = (unsigned short*)(wsb + szAv + szAq);   // bf16 M2*256
    unsigned short* Bv   = (unsigned short*)(wsb + szAv + szAq + (size_t)M2 * 256 * 2);
    unsigned short* Bo   = Bv + 256 * 512;
    unsigned short* Blg  = Bo + 256 * 512;
    float*          lgt  = (float*)d_out;            // scratch until final GEMM

    const int mb1 = (M1 + 31) / 32;
    const int mb2 = (M2 + 31) / 32;
    const int nbAct = ((M2 + M1) * 64 + 255) / 256;

    // 1) ALL conversions in one launch (activations + 4 weight matrices)
    convall<<<dim3(nbAct + 192), blk, 0, stream>>>(
        value, query, Av, Aq, M2, M2 + M1, nbAct,
        vproj_w, oproj_w, attn_w, box_w, Bv, Bo, Blg);

    // 2) MERGED: value projection (+mask, bf16 out) AND combined logits (f32)
    gemm_mfma<0><<<dim3(mb2 + mb1), blk, 0, stream>>>(
        Av, Bv, vproj_b, vproj_b, 256, v_mask, (void*)vprj, 1, M2, mb2,
        Aq, Blg, attn_b, box_b, 128, nullptr, (void*)lgt, 0, M1);

    // 3) sampling (bf16 v gathers, point-split, TLP) -> split-bf16
    box_sample<<<dim3((M1 + ROWS - 1) / ROWS), blk, 0, stream>>>(
        vprj, lgt, lgt + 128, ref_win, v_valid, OutS, M1, L1, L2);

    // 4) output projection (reads OutS, overwrites d_out)
    gemm_mfma<1><<<dim3(mb1), blk, 0, stream>>>(
        OutS, Bo, oproj_b, oproj_b, 256, nullptr, d_out, 0, M1, mb1,
        OutS, Bo, oproj_b, oproj_b, 256, nullptr, d_out, 0, M1);
}

// Round 27
// 91.175 us; speedup vs baseline: 1.3915x; 1.0684x over previous
//
#include <hip/hip_runtime.h>
#include <cstdint>
#include <cstddef>

#define NHEAD 8
#define HDIM 32
#define DMODEL 256
#define NLEVEL 4
#define NPOINT 4

using short8 = __attribute__((ext_vector_type(8))) short;
using f32x4  = __attribute__((ext_vector_type(4))) float;

// ---- bf16 helpers (RNE) ----------------------------------------------------
__device__ __forceinline__ unsigned short f2bf(float x) {
    unsigned int b = __float_as_uint(x);
    unsigned int r = b + 0x7FFFu + ((b >> 16) & 1u);
    return (unsigned short)(r >> 16);
}
__device__ __forceinline__ float bf2f(unsigned short u) {
    return __uint_as_float(((unsigned int)u) << 16);
}
__device__ __forceinline__ unsigned short lo1(float v) {
    const unsigned short h = f2bf(v);
    return f2bf(v - bf2f(h));
}
__device__ __forceinline__ unsigned int pk2(unsigned short a, unsigned short b) {
    return (unsigned int)a | ((unsigned int)b << 16);
}

// ---------------------------------------------------------------------------
// convall: ONE launch for all conversions.
//   blocks [0, nbAct): value -> Av, query -> Aq  ([hi|lo] per row)
//   blocks [nbAct, nbAct+192): four weight matrices -> Bv, Bo, Blg
// ---------------------------------------------------------------------------
__global__ __launch_bounds__(256) void convall(
    const float* __restrict__ value, const float* __restrict__ query,
    unsigned short* __restrict__ Av, unsigned short* __restrict__ Aq,
    int M2, int Mtot, int nbAct,
    const float* __restrict__ w0, const float* __restrict__ w1,
    const float* __restrict__ w2, const float* __restrict__ w3,
    unsigned short* __restrict__ b0, unsigned short* __restrict__ b1,
    unsigned short* __restrict__ blg)
{
    if ((int)blockIdx.x < nbAct) {
        const int idx = blockIdx.x * 256 + threadIdx.x;
        if (idx >= Mtot * 64) return;
        const int r = idx >> 6, c = (idx & 63) << 2;
        const float* src;
        unsigned short* dst;
        if (r < M2) { src = value + (size_t)r * 256; dst = Av + (size_t)r * 512; }
        else { src = query + (size_t)(r - M2) * 256; dst = Aq + (size_t)(r - M2) * 512; }
        const float4 v = *(const float4*)(src + c);
        ushort4 hi, lo;
        hi.x = f2bf(v.x); lo.x = lo1(v.x);
        hi.y = f2bf(v.y); lo.y = lo1(v.y);
        hi.z = f2bf(v.z); lo.z = lo1(v.z);
        hi.w = f2bf(v.w); lo.w = lo1(v.w);
        *(ushort4*)(dst + c)       = hi;
        *(ushort4*)(dst + 256 + c) = lo;
    } else {
        const int bx = (int)blockIdx.x - nbAct;           // 0..191
        int y, base;
        if (bx < 64)       { y = 0; base = bx; }
        else if (bx < 128) { y = 1; base = bx - 64; }
        else if (bx < 160) { y = 2; base = bx - 128; }
        else               { y = 3; base = bx - 160; }
        const float* src = (y == 0) ? w0 : (y == 1) ? w1 : (y == 2) ? w2 : w3;
        unsigned short* dst = (y == 0) ? b0 : (y == 1) ? b1 : (y == 2) ? blg : (blg + 128 * 512);
        const int rows = (y < 2) ? 256 : 128;
        const int idx = base * 256 + threadIdx.x;
        if (idx >= rows * 64) return;
        const int r = idx >> 6, c = (idx & 63) << 2;
        const float4 v = *(const float4*)(src + (size_t)r * 256 + c);
        ushort4 hi, lo;
        hi.x = f2bf(v.x); lo.x = lo1(v.x);
        hi.y = f2bf(v.y); lo.y = lo1(v.y);
        hi.z = f2bf(v.z); lo.z = lo1(v.z);
        hi.w = f2bf(v.w); lo.w = lo1(v.w);
        *(ushort4*)(dst + (size_t)r * 512 + c)       = hi;
        *(ushort4*)(dst + (size_t)r * 512 + 256 + c) = lo;
    }
}

// ---------------------------------------------------------------------------
// Split-bf16 MFMA GEMM, BM=32 x BN=256, BK=64, single-buffered, 1-deep
// register prefetch (R24/R26-proven). LDS 36KB, swizzle phys_row=row^(slot<<1).
// Per-sub step count nst (block-uniform):
//   nst=12: K'=768, A [hi,hi,lo] x B [hi,lo,hi]  (C = AhBh+AhBl+AlBh; ~f32)
//   nst=8:  K'=512, A [hi,lo]    x B [hi,hi]     (C = A*Bh; err ~2^-9 rel)
// nst=8 is used where the output is bf16-rounded anyway (vprj) or where the
// input already carries bf16 rounding (out-proj): precision matched to sink.
// Logits keep nst=12 (coordinates -> floor()/border: discontinuous path).
// obf: bf16 C-write for vprj.
// ---------------------------------------------------------------------------
__device__ __forceinline__ void seg_offs(int sn, int nst, int& aoff, int& boff) {
    const int kl = (sn & 3) << 6;                 // 0,64,128,192 ushorts
    if (nst == 8) {
        aoff = ((sn >> 2) ? 256 : 0) + kl;        // A: [hi,lo]
        boff = kl;                                // B: [hi,hi]
    } else {
        const int seg = sn >> 2;                  // 0..2
        aoff = ((seg < 2) ? 0 : 256) + kl;        // A: [hi,hi,lo]
        boff = ((seg == 1) ? 256 : 0) + kl;       // B: [hi,lo,hi]
    }
}

template<int ID>
__global__ __launch_bounds__(256, 4) void gemm_mfma(
    const unsigned short* __restrict__ A0, const unsigned short* __restrict__ B0,
    const float* __restrict__ bsA0, const float* __restrict__ bsB0, int bsplit0,
    const unsigned char* __restrict__ mask0, void* __restrict__ C0, int obf0,
    int nst0, int M0, int nb0,
    const unsigned short* __restrict__ A1, const unsigned short* __restrict__ B1,
    const float* __restrict__ bsA1, const float* __restrict__ bsB1, int bsplit1,
    const unsigned char* __restrict__ mask1, void* __restrict__ C1, int obf1,
    int nst1, int M1)
{
    __shared__ __align__(16) unsigned short As[8 * 32 * 8];    // 4KB  [slot][32][8]
    __shared__ __align__(16) unsigned short Bs[8 * 256 * 8];   // 32KB [slot][256][8]

    const bool second = ((int)blockIdx.x >= nb0);
    const unsigned short* Abf = second ? A1 : A0;
    const unsigned short* Bbf = second ? B1 : B0;
    const float* biasA = second ? bsA1 : bsA0;
    const float* biasB = second ? bsB1 : bsB0;
    const int bsplit   = second ? bsplit1 : bsplit0;
    const unsigned char* maskp = second ? mask1 : mask0;
    void* Cv    = second ? C1 : C0;
    const int obf = second ? obf1 : obf0;
    const int nst = second ? nst1 : nst0;
    const int M = second ? M1 : M0;
    const int row0 = (second ? ((int)blockIdx.x - nb0) : (int)blockIdx.x) * 32;

    const int tid  = threadIdx.x;
    const int lane = tid & 63;
    const int wave = tid >> 6;          // 0..3 -> cols wave*64..+64
    const int lr = lane & 15;
    const int kg = lane >> 4;           // 0..3 k-octet group within K=32

    // staging maps (1 A + 8 B loads per thread)
    const int as = tid & 7;             // A slot 0..7
    const int ar = tid >> 3;            // A row 0..31
    const int arx = ar ^ (as << 1);
    const int bs = tid & 7;             // B slot 0..7
    const int br = tid >> 3;            // B row base 0..31 (8 rows stride 32)

    const unsigned short* pA = Abf + (size_t)min(row0 + ar, M - 1) * 512 + as * 8;
    const unsigned short* pB = Bbf + (size_t)br * 512 + bs * 8;

    f32x4 acc[2][4];
#pragma unroll
    for (int m = 0; m < 2; ++m)
#pragma unroll
        for (int n = 0; n < 4; ++n) acc[m][n] = {0.f, 0.f, 0.f, 0.f};

    // prefetch step 0 (both schedules: aoff=boff=0)
    uint4 va, vb0, vb1, vb2, vb3, vb4, vb5, vb6, vb7;
    va  = *(const uint4*)pA;
    vb0 = *(const uint4*)(pB                   );
    vb1 = *(const uint4*)(pB + (size_t) 32*512);
    vb2 = *(const uint4*)(pB + (size_t) 64*512);
    vb3 = *(const uint4*)(pB + (size_t) 96*512);
    vb4 = *(const uint4*)(pB + (size_t)128*512);
    vb5 = *(const uint4*)(pB + (size_t)160*512);
    vb6 = *(const uint4*)(pB + (size_t)192*512);
    vb7 = *(const uint4*)(pB + (size_t)224*512);

    for (int st = 0; st < nst; ++st) {
        *(uint4*)&As[as * 256 + arx * 8] = va;
        *(uint4*)&Bs[bs * 2048 + (((br      ) ^ (bs << 1))      ) * 8] = vb0;
        *(uint4*)&Bs[bs * 2048 + (((br      ) ^ (bs << 1)) +  32) * 8] = vb1;
        *(uint4*)&Bs[bs * 2048 + (((br      ) ^ (bs << 1)) +  64) * 8] = vb2;
        *(uint4*)&Bs[bs * 2048 + (((br      ) ^ (bs << 1)) +  96) * 8] = vb3;
        *(uint4*)&Bs[bs * 2048 + (((br      ) ^ (bs << 1)) + 128) * 8] = vb4;
        *(uint4*)&Bs[bs * 2048 + (((br      ) ^ (bs << 1)) + 160) * 8] = vb5;
        *(uint4*)&Bs[bs * 2048 + (((br      ) ^ (bs << 1)) + 192) * 8] = vb6;
        *(uint4*)&Bs[bs * 2048 + (((br      ) ^ (bs << 1)) + 224) * 8] = vb7;
        __syncthreads();   // writes visible before reads

        if (st < nst - 1) {   // issue next step's loads; hide under 16 MFMAs
            int aoff, boff;
            seg_offs(st + 1, nst, aoff, boff);
            va  = *(const uint4*)(pA + aoff);
            vb0 = *(const uint4*)(pB + boff                   );
            vb1 = *(const uint4*)(pB + boff + (size_t) 32*512);
            vb2 = *(const uint4*)(pB + boff + (size_t) 64*512);
            vb3 = *(const uint4*)(pB + boff + (size_t) 96*512);
            vb4 = *(const uint4*)(pB + boff + (size_t)128*512);
            vb5 = *(const uint4*)(pB + boff + (size_t)160*512);
            vb6 = *(const uint4*)(pB + boff + (size_t)192*512);
            vb7 = *(const uint4*)(pB + boff + (size_t)224*512);
        }

#pragma unroll
        for (int ks = 0; ks < 2; ++ks) {
            const int sA = ks * 4 + kg;               // octet slot 0..7
            const int rx = lr ^ (sA << 1);
            const short8 a0 = *(const short8*)&As[sA * 256 + (rx     ) * 8];
            const short8 a1 = *(const short8*)&As[sA * 256 + (rx + 16) * 8];
#pragma unroll
            for (int n = 0; n < 4; ++n) {
                const short8 bb = *(const short8*)&Bs[sA * 2048 + (wave * 64 + n * 16 + rx) * 8];
                acc[0][n] = __builtin_amdgcn_mfma_f32_16x16x32_bf16(a0, bb, acc[0][n], 0, 0, 0);
                acc[1][n] = __builtin_amdgcn_mfma_f32_16x16x32_bf16(a1, bb, acc[1][n], 0, 0, 0);
            }
        }
        __syncthreads();   // reads done before next step's writes
    }

    // epilogue: C/D layout col=lane&15, row=(lane>>4)*4+j  [m89-verified]
#pragma unroll
    for (int m = 0; m < 2; ++m) {
#pragma unroll
        for (int n = 0; n < 4; ++n) {
            const int colg = wave * 64 + n * 16 + lr;
            const float bias = (colg < bsplit) ? biasA[colg] : biasB[colg - bsplit];
#pragma unroll
            for (int j = 0; j < 4; ++j) {
                const int rowg = row0 + m * 16 + kg * 4 + j;
                if (rowg < M) {
                    float o = acc[m][n][j] + bias;
                    if (maskp && maskp[rowg]) o = 0.f;
                    if (obf) ((unsigned short*)Cv)[(size_t)rowg * 256 + colg] = f2bf(o);
                    else     ((float*)Cv)[(size_t)rowg * 256 + colg] = o;
                }
            }
        }
    }
}

// ---------------------------------------------------------------------------
// Box-attention sampling (R21-proven: ~37us). bf16-v + point-split + TLP
// (__launch_bounds__(256,5), unroll 4). Output: split-bf16 [hi|lo].
// ---------------------------------------------------------------------------
#define ROWS 4
#define PP 17

__global__ __launch_bounds__(256, 5) void box_sample(
    const unsigned short* __restrict__ v, // (B*L2, 256) bf16 projected value
    const float* __restrict__ alogp,  // attn logits base (stride 256)
    const float* __restrict__ blgp,   // box logits base (stride 256)
    const float* __restrict__ rwin,
    const float* __restrict__ vratio,
    unsigned short* __restrict__ outs, // (B*L1, 512) split-bf16 out
    int M1, int L1, int L2)
{
    __shared__ int   s_idx[ROWS][NHEAD][PP][4];
    __shared__ float s_w  [ROWS][NHEAD][PP][4];
    __shared__ float s_red[ROWS][NHEAD][4][8];   // point-half reduction (4KB)

    const int row0 = blockIdx.x * ROWS;
    const int tid  = threadIdx.x;

    // ================= phase 1 (first 128 threads) =================
    if (tid < 128) {
        const int l  = tid & 3;
        const int hh = (tid >> 2) & 7;
        const int r  = tid >> 5;
        const int rowq = row0 + r;
        if (rowq < M1) {
            const int b = (rowq >= L1) ? 1 : 0;
            float la[16];
            const float* al = alogp + (size_t)rowq * 256 + hh * 16;
            {
                const float4 q0 = *(const float4*)(al + 0);
                const float4 q1 = *(const float4*)(al + 4);
                const float4 q2 = *(const float4*)(al + 8);
                const float4 q3 = *(const float4*)(al + 12);
                la[0]=q0.x; la[1]=q0.y; la[2]=q0.z; la[3]=q0.w;
                la[4]=q1.x; la[5]=q1.y; la[6]=q1.z; la[7]=q1.w;
                la[8]=q2.x; la[9]=q2.y; la[10]=q2.z; la[11]=q2.w;
                la[12]=q3.x; la[13]=q3.y; la[14]=q3.z; la[15]=q3.w;
            }
            float m = la[0];
#pragma unroll
            for (int i = 1; i < 16; i++) m = fmaxf(m, la[i]);
            float s = 0.f;
#pragma unroll
            for (int i = 0; i < 16; i++) { la[i] = __expf(la[i] - m); s += la[i]; }
            const float inv = 1.f / s;

            const int H  = (l == 0) ? 76 : (l == 1) ? 38 : (l == 2) ? 19 : 10;
            const int W  = H;
            const int s0 = (l == 0) ? 0  : (l == 1) ? 5776 : (l == 2) ? 7220 : 7581;

            const float4 ob = *(const float4*)(blgp + (size_t)rowq * 256 + hh * 16 + l * 4);
            const float4 rw = *(const float4*)(rwin + (size_t)rowq * 4);
            const float vrx = vratio[(b * NLEVEL + l) * 2 + 0];
            const float vry = vratio[(b * NLEVEL + l) * 2 + 1];

            const float cx = rw.x + ob.x * 0.125f * rw.z;
            const float cy = rw.y + ob.y * 0.125f * rw.w;
            const float sw = fmaxf(rw.z + ob.z * 0.125f * rw.z, 0.f);
            const float sh = fmaxf(rw.w + ob.w * 0.125f * rw.w, 0.f);

            const int vbase = (b * L2 + s0) * DMODEL + hh * HDIM;  // ushort units

#pragma unroll
            for (int p = 0; p < 4; ++p) {
                const float kx = (p & 1)  ? 0.25f : -0.25f;
                const float ky = (p >> 1) ? 0.25f : -0.25f;
                const float gx = (cx + kx * sw) * vrx;
                const float gy = (cy + ky * sh) * vry;
                const float x = gx * (float)W - 0.5f;
                const float y = gy * (float)H - 0.5f;
                const float x0f = floorf(x);
                const float y0f = floorf(y);
                const float lx = x - x0f, ly = y - y0f;
                const int x0 = (int)x0f, y0 = (int)y0f;
                const float aw = la[l * 4 + p] * inv;
                const float wb[4] = { (1.f - ly) * (1.f - lx) * aw,
                                      (1.f - ly) * lx * aw,
                                      ly * (1.f - lx) * aw,
                                      ly * lx * aw };
                const int lp = l * 4 + p;
#pragma unroll
                for (int j = 0; j < 4; ++j) {
                    const int yy = y0 + (j >> 1);
                    const int xx = x0 + (j & 1);
                    const bool ok = (yy >= 0) & (yy < H) & (xx >= 0) & (xx < W);
                    const int yc = min(max(yy, 0), H - 1);
                    const int xc = min(max(xx, 0), W - 1);
                    s_idx[r][hh][lp][j] = vbase + (yc * W + xc) * DMODEL;
                    s_w  [r][hh][lp][j] = ok ? wb[j] : 0.f;
                }
            }
        }
    }
    __syncthreads();

    // ================= phase 2: point-split ushort8 gathers =================
    {
        const int oct = tid & 3;            // channel octet 0..3
        const int hh  = (tid >> 2) & 7;     // head
        const int ph  = (tid >> 5) & 1;     // point half
        const int r   = tid >> 6;           // row 0..3
        const int rowq = row0 + r;
        const int c8 = oct << 3;
        float acc[8];
#pragma unroll
        for (int k = 0; k < 8; ++k) acc[k] = 0.f;

        if (rowq < M1) {
            const int p0 = ph << 3;
#pragma unroll 4
            for (int pi = 0; pi < 8; ++pi) {
                const int p = p0 + pi;
                const int4   iv = *(const int4  *)&s_idx[r][hh][p][0];
                const float4 wv = *(const float4*)&s_w  [r][hh][p][0];
                const uint4 g0 = *(const uint4*)(v + iv.x + c8);
                const uint4 g1 = *(const uint4*)(v + iv.y + c8);
                const uint4 g2 = *(const uint4*)(v + iv.z + c8);
                const uint4 g3 = *(const uint4*)(v + iv.w + c8);
                const unsigned int u0[4] = {g0.x, g0.y, g0.z, g0.w};
                const unsigned int u1[4] = {g1.x, g1.y, g1.z, g1.w};
                const unsigned int u2[4] = {g2.x, g2.y, g2.z, g2.w};
                const unsigned int u3[4] = {g3.x, g3.y, g3.z, g3.w};
#pragma unroll
                for (int j = 0; j < 4; ++j) {
                    const float a0 = __uint_as_float(u0[j] << 16);
                    const float b0 = __uint_as_float(u0[j] & 0xffff0000u);
                    const float a1 = __uint_as_float(u1[j] << 16);
                    const float b1 = __uint_as_float(u1[j] & 0xffff0000u);
                    const float a2 = __uint_as_float(u2[j] << 16);
                    const float b2 = __uint_as_float(u2[j] & 0xffff0000u);
                    const float a3 = __uint_as_float(u3[j] << 16);
                    const float b3 = __uint_as_float(u3[j] & 0xffff0000u);
                    acc[j * 2]     += wv.x * a0 + wv.y * a1 + wv.z * a2 + wv.w * a3;
                    acc[j * 2 + 1] += wv.x * b0 + wv.y * b1 + wv.z * b2 + wv.w * b3;
                }
            }
        }

        // reduce the two point-halves via LDS
        if (ph == 1) {
#pragma unroll
            for (int k = 0; k < 8; ++k) s_red[r][hh][oct][k] = acc[k];
        }
        __syncthreads();
        if (ph == 0 && rowq < M1) {
#pragma unroll
            for (int k = 0; k < 8; ++k) acc[k] += s_red[r][hh][oct][k];
            uint4 hi, lo;
            hi.x = pk2(f2bf(acc[0]), f2bf(acc[1]));
            hi.y = pk2(f2bf(acc[2]), f2bf(acc[3]));
            hi.z = pk2(f2bf(acc[4]), f2bf(acc[5]));
            hi.w = pk2(f2bf(acc[6]), f2bf(acc[7]));
            lo.x = pk2(lo1(acc[0]), lo1(acc[1]));
            lo.y = pk2(lo1(acc[2]), lo1(acc[3]));
            lo.z = pk2(lo1(acc[4]), lo1(acc[5]));
            lo.w = pk2(lo1(acc[6]), lo1(acc[7]));
            *(uint4*)(outs + (size_t)rowq * 512 + hh * HDIM + c8)       = hi;
            *(uint4*)(outs + (size_t)rowq * 512 + 256 + hh * HDIM + c8) = lo;
        }
    }
}

// ---------------------------------------------------------------------------
extern "C" void kernel_launch(void* const* d_in, const int* in_sizes, int n_in,
                              void* d_out, int out_size, void* d_ws, size_t ws_size,
                              hipStream_t stream) {
    const float* query   = (const float*)d_in[0];
    const float* value   = (const float*)d_in[1];
    const unsigned char* v_mask = (const unsigned char*)d_in[3];
    const float* v_valid = (const float*)d_in[5];
    const float* ref_win = (const float*)d_in[6];
    const float* vproj_w = (const float*)d_in[7];
    const float* vproj_b = (const float*)d_in[8];
    const float* oproj_w = (const float*)d_in[9];
    const float* oproj_b = (const float*)d_in[10];
    const float* box_w   = (const float*)d_in[11];
    const float* box_b   = (const float*)d_in[12];
    const float* attn_w  = (const float*)d_in[13];
    const float* attn_b  = (const float*)d_in[14];

    const int B  = 2;
    const int M1 = in_sizes[0] / DMODEL;   // B*L1
    const int M2 = in_sizes[1] / DMODEL;   // B*L2
    const int L1 = M1 / B;
    const int L2 = M2 / B;
    const dim3 blk(256);

    // ---- workspace plan: Av | Aq(->OutS) | vprj(bf16) | weights; lgt in d_out
    const size_t szAv = (size_t)M2 * 512 * 2;
    const size_t szAq = (size_t)M1 * 512 * 2;
    char* wsb = (char*)d_ws;
    unsigned short* Av   = (unsigned short*)(wsb);
    unsigned short* Aq   = (unsigned short*)(wsb + szAv);
    unsigned short* OutS = Aq;                       // alias: Aq dead after GEMM
    unsigned short* vprj = (unsigned short*)(wsb + szAv + szAq);   // bf16 M2*256
    unsigned short* Bv   = (unsigned short*)(wsb + szAv + szAq + (size_t)M2 * 256 * 2);
    unsigned short* Bo   = Bv + 256 * 512;
    unsigned short* Blg  = Bo + 256 * 512;
    float*          lgt  = (float*)d_out;            // scratch until final GEMM

    const int mb1 = (M1 + 31) / 32;
    const int mb2 = (M2 + 31) / 32;
    const int nbAct = ((M2 + M1) * 64 + 255) / 256;

    // 1) ALL conversions in one launch (activations + 4 weight matrices)
    convall<<<dim3(nbAct + 192), blk, 0, stream>>>(
        value, query, Av, Aq, M2, M2 + M1, nbAct,
        vproj_w, oproj_w, attn_w, box_w, Bv, Bo, Blg);

    // 2) MERGED: value projection (+mask, bf16 out, K'=512) AND logits (K'=768)
    gemm_mfma<0><<<dim3(mb2 + mb1), blk, 0, stream>>>(
        Av, Bv, vproj_b, vproj_b, 256, v_mask, (void*)vprj, 1, 8, M2, mb2,
        Aq, Blg, attn_b, box_b, 128, nullptr, (void*)lgt, 0, 12, M1);

    // 3) sampling (bf16 v gathers, point-split, TLP) -> split-bf16
    box_sample<<<dim3((M1 + ROWS - 1) / ROWS), blk, 0, stream>>>(
        vprj, lgt, lgt + 128, ref_win, v_valid, OutS, M1, L1, L2);

    // 4) output projection (K'=512; input hi already bf16-rounded)
    gemm_mfma<1><<<dim3(mb1), blk, 0, stream>>>(
        OutS, Bo, oproj_b, oproj_b, 256, nullptr, d_out, 0, 8, M1, mb1,
        OutS, Bo, oproj_b, oproj_b, 256, nullptr, d_out, 0, 8, M1);
}